// Round 1
// baseline (307.622 us; speedup 1.0000x reference)
//
#include <hip/hip_runtime.h>
#include <hip/hip_bf16.h>
#include <cstdint>

#define B_ 8
#define C_ 128
#define N_ 16384  // H*W = 128*128

typedef __attribute__((ext_vector_type(8))) short short8;
typedef __attribute__((ext_vector_type(4))) float f32x4;
typedef unsigned short u16;

__device__ __forceinline__ short f2bf(float f) {
  union { float f; unsigned u; } c; c.f = f;
  unsigned r = (c.u + 0x7FFFu + ((c.u >> 16) & 1u)) >> 16;
  return (short)r;
}

// ---------------------------------------------------------------------------
// K1: EK = exp(k_w·x + k_b), V = v_w·x + v_b  (bf16 to ws), Z[d] += sum_n EK
// grid (N/64, B), 256 thr = 4 waves; wave (wr,wc): 64 rows x 32 cols
// ---------------------------------------------------------------------------
__global__ __launch_bounds__(256) void k1_proj(
    const float* __restrict__ kv, const float* __restrict__ kw,
    const float* __restrict__ kb, const float* __restrict__ vw,
    const float* __restrict__ vb, u16* __restrict__ EK, u16* __restrict__ V,
    float* __restrict__ Z) {
  const int b = blockIdx.y;
  const int n_base = blockIdx.x * 64;
  const int tid = threadIdx.x;
  const int wave = tid >> 6, lane = tid & 63;
  const int wr = wave >> 1, wc = wave & 1;
  const int lg = lane >> 4, li = lane & 15;
  const float* x = kv + (size_t)b * C_ * N_;

  f32x4 acck[4][2] = {};
  f32x4 accv[4][2] = {};
#pragma unroll
  for (int ks = 0; ks < 4; ++ks) {
    const int e0 = ks * 32 + lg * 8;
    short8 ak[4], av[4];
#pragma unroll
    for (int mt = 0; mt < 4; ++mt) {
      const int row = wr * 64 + mt * 16 + li;
      const float4* kp = reinterpret_cast<const float4*>(kw + row * C_ + e0);
      const float4* vp = reinterpret_cast<const float4*>(vw + row * C_ + e0);
      float4 k0 = kp[0], k1 = kp[1];
      float4 v0 = vp[0], v1 = vp[1];
      short8 tk, tv;
      tk[0] = f2bf(k0.x); tk[1] = f2bf(k0.y); tk[2] = f2bf(k0.z); tk[3] = f2bf(k0.w);
      tk[4] = f2bf(k1.x); tk[5] = f2bf(k1.y); tk[6] = f2bf(k1.z); tk[7] = f2bf(k1.w);
      tv[0] = f2bf(v0.x); tv[1] = f2bf(v0.y); tv[2] = f2bf(v0.z); tv[3] = f2bf(v0.w);
      tv[4] = f2bf(v1.x); tv[5] = f2bf(v1.y); tv[6] = f2bf(v1.z); tv[7] = f2bf(v1.w);
      ak[mt] = tk; av[mt] = tv;
    }
    short8 bx[2];
#pragma unroll
    for (int nt = 0; nt < 2; ++nt) {
      const int n = n_base + wc * 32 + nt * 16 + li;
      const float* xp = x + (size_t)e0 * N_ + n;
      short8 t;
#pragma unroll
      for (int j = 0; j < 8; ++j) t[j] = f2bf(xp[(size_t)j * N_]);
      bx[nt] = t;
    }
#pragma unroll
    for (int mt = 0; mt < 4; ++mt)
#pragma unroll
      for (int nt = 0; nt < 2; ++nt) {
        acck[mt][nt] = __builtin_amdgcn_mfma_f32_16x16x32_bf16(ak[mt], bx[nt], acck[mt][nt], 0, 0, 0);
        accv[mt][nt] = __builtin_amdgcn_mfma_f32_16x16x32_bf16(av[mt], bx[nt], accv[mt][nt], 0, 0, 0);
      }
  }
  // epilogue: bias, exp, store bf16, Z reduction
#pragma unroll
  for (int mt = 0; mt < 4; ++mt) {
#pragma unroll
    for (int r = 0; r < 4; ++r) {
      const int d = wr * 64 + mt * 16 + lg * 4 + r;
      const float kbias = kb[d];
      const float vbias = vb[d];
      float zp = 0.f;
#pragma unroll
      for (int nt = 0; nt < 2; ++nt) {
        const int n = n_base + wc * 32 + nt * 16 + li;
        const float ek = __expf(acck[mt][nt][r] + kbias);
        const float vv = accv[mt][nt][r] + vbias;
        const size_t o = ((size_t)b * C_ + d) * N_ + n;
        EK[o] = (u16)f2bf(ek);
        V[o] = (u16)f2bf(vv);
        zp += ek;
      }
      // reduce over the 16 lanes of this group (same d)
#pragma unroll
      for (int off = 1; off < 16; off <<= 1) zp += __shfl_xor(zp, off);
      if (li == 0) atomicAdd(&Z[b * C_ + d], zp);
    }
  }
}

// ---------------------------------------------------------------------------
// K2: context partials: part[kc][b][c][d] = sum_{n in chunk} V[c,n]*EK[d,n]
// grid (32, B), 512 thr = 8 waves; wave: 16 rows(c) x 128 cols(d); K=512/chunk
// ---------------------------------------------------------------------------
__global__ __launch_bounds__(512) void k2_ctx(const u16* __restrict__ EK,
                                              const u16* __restrict__ V,
                                              float* __restrict__ part) {
  const int b = blockIdx.y, kc = blockIdx.x;
  const int tid = threadIdx.x;
  const int wave = tid >> 6, lane = tid & 63;
  const int lg = lane >> 4, li = lane & 15;
  const u16* Vb = V + (size_t)b * C_ * N_;
  const u16* Eb = EK + (size_t)b * C_ * N_;
  f32x4 acc[8] = {};
#pragma unroll 4
  for (int s = 0; s < 16; ++s) {
    const int n0 = kc * 512 + s * 32 + lg * 8;
    short8 a = *reinterpret_cast<const short8*>(Vb + (size_t)(wave * 16 + li) * N_ + n0);
    short8 bf[8];
#pragma unroll
    for (int nt = 0; nt < 8; ++nt)
      bf[nt] = *reinterpret_cast<const short8*>(Eb + (size_t)(nt * 16 + li) * N_ + n0);
#pragma unroll
    for (int nt = 0; nt < 8; ++nt)
      acc[nt] = __builtin_amdgcn_mfma_f32_16x16x32_bf16(a, bf[nt], acc[nt], 0, 0, 0);
  }
  float* out = part + ((size_t)kc * B_ + b) * C_ * C_;
#pragma unroll
  for (int nt = 0; nt < 8; ++nt)
#pragma unroll
    for (int r = 0; r < 4; ++r) {
      const int c = wave * 16 + lg * 4 + r;
      const int d = nt * 16 + li;
      out[c * C_ + d] = acc[nt][r];
    }
}

// ---------------------------------------------------------------------------
// K3: cs = (sum_p part)/Z ; M = cs·q_w (bf16), T = cs·q_b
// grid (8, B), 256 thr; each block: 16 c-rows
// ---------------------------------------------------------------------------
__global__ __launch_bounds__(256) void k3_fin(const float* __restrict__ part,
                                              const float* __restrict__ Z,
                                              const float* __restrict__ qw,
                                              const float* __restrict__ qb,
                                              u16* __restrict__ M,
                                              float* __restrict__ T) {
  const int b = blockIdx.y;
  const int cs0 = blockIdx.x * 16;
  const int tid = threadIdx.x;
  __shared__ float cs[16][128];
#pragma unroll
  for (int i = 0; i < 8; ++i) {
    const int e = tid + i * 256;
    const int cl = e >> 7, d = e & 127;
    float s = 0.f;
    for (int p = 0; p < 32; ++p)
      s += part[(((size_t)p * B_ + b) * C_ + (cs0 + cl)) * C_ + d];
    cs[cl][d] = s / Z[b * C_ + d];
  }
  __syncthreads();
  const int cl = tid >> 4, e0 = (tid & 15) * 8;
  float m[8] = {};
  for (int d = 0; d < 128; ++d) {
    const float cv = cs[cl][d];
    const float* qr = qw + d * C_ + e0;
#pragma unroll
    for (int j = 0; j < 8; ++j) m[j] += cv * qr[j];
  }
  u16* mp = M + ((size_t)b * C_ + cs0 + cl) * C_ + e0;
#pragma unroll
  for (int j = 0; j < 8; ++j) mp[j] = (u16)f2bf(m[j]);
  if (tid < 16) {
    float tv = 0.f;
    for (int d = 0; d < 128; ++d) tv += cs[tid][d] * qb[d];
    T[b * C_ + cs0 + tid] = tv;
  }
}

// ---------------------------------------------------------------------------
// K4: out = M·q_feat + T   (fp32 out)
// grid (N/128, B), 256 thr = 4 waves; wave: 32 rows(c) x 128 cols(n)
// ---------------------------------------------------------------------------
__global__ __launch_bounds__(256) void k4_out(const u16* __restrict__ M,
                                              const float* __restrict__ T,
                                              const float* __restrict__ q,
                                              float* __restrict__ out) {
  const int b = blockIdx.y;
  const int n_base = blockIdx.x * 128;
  const int tid = threadIdx.x;
  const int wave = tid >> 6, lane = tid & 63;
  const int lg = lane >> 4, li = lane & 15;
  const float* x = q + (size_t)b * C_ * N_;
  const u16* Mb = M + (size_t)b * C_ * C_;
  f32x4 acc[2][8] = {};
#pragma unroll
  for (int ks = 0; ks < 4; ++ks) {
    const int e0 = ks * 32 + lg * 8;
    short8 a[2];
#pragma unroll
    for (int mt = 0; mt < 2; ++mt)
      a[mt] = *reinterpret_cast<const short8*>(Mb + (wave * 32 + mt * 16 + li) * C_ + e0);
    short8 bx[8];
#pragma unroll
    for (int nt = 0; nt < 8; ++nt) {
      const int n = n_base + nt * 16 + li;
      const float* xp = x + (size_t)e0 * N_ + n;
      short8 t;
#pragma unroll
      for (int j = 0; j < 8; ++j) t[j] = f2bf(xp[(size_t)j * N_]);
      bx[nt] = t;
    }
#pragma unroll
    for (int mt = 0; mt < 2; ++mt)
#pragma unroll
      for (int nt = 0; nt < 8; ++nt)
        acc[mt][nt] = __builtin_amdgcn_mfma_f32_16x16x32_bf16(a[mt], bx[nt], acc[mt][nt], 0, 0, 0);
  }
#pragma unroll
  for (int mt = 0; mt < 2; ++mt)
#pragma unroll
    for (int r = 0; r < 4; ++r) {
      const int c = wave * 32 + mt * 16 + lg * 4 + r;
      const float tc = T[b * C_ + c];
      float* op = out + ((size_t)b * C_ + c) * N_ + n_base;
#pragma unroll
      for (int nt = 0; nt < 8; ++nt)
        op[nt * 16 + li] = acc[mt][nt][r] + tc;
    }
}

// ---------------------------------------------------------------------------
extern "C" void kernel_launch(void* const* d_in, const int* in_sizes, int n_in,
                              void* d_out, int out_size, void* d_ws, size_t ws_size,
                              hipStream_t stream) {
  const float* q_feat  = (const float*)d_in[0];
  const float* kv_feat = (const float*)d_in[1];
  const float* q_w = (const float*)d_in[2];
  const float* q_b = (const float*)d_in[3];
  const float* k_w = (const float*)d_in[4];
  const float* k_b = (const float*)d_in[5];
  const float* v_w = (const float*)d_in[6];
  const float* v_b = (const float*)d_in[7];
  float* out = (float*)d_out;

  char* ws = (char*)d_ws;
  const size_t szEV  = (size_t)B_ * C_ * N_ * sizeof(u16);   // 32 MB each
  const size_t szZ   = (size_t)B_ * C_ * sizeof(float);      // 4 KB
  const size_t szPar = (size_t)32 * B_ * C_ * C_ * sizeof(float); // 16 MB
  const size_t szM   = (size_t)B_ * C_ * C_ * sizeof(u16);   // 256 KB

  u16*   EK   = (u16*)ws;
  u16*   V    = (u16*)(ws + szEV);
  float* Z    = (float*)(ws + 2 * szEV);
  float* part = (float*)(ws + 2 * szEV + szZ);
  u16*   M    = (u16*)(ws + 2 * szEV + szZ + szPar);
  float* T    = (float*)(ws + 2 * szEV + szZ + szPar + szM);

  hipMemsetAsync(Z, 0, szZ, stream);
  k1_proj<<<dim3(N_ / 64, B_), 256, 0, stream>>>(kv_feat, k_w, k_b, v_w, v_b, EK, V, Z);
  k2_ctx<<<dim3(32, B_), 512, 0, stream>>>(EK, V, part);
  k3_fin<<<dim3(8, B_), 256, 0, stream>>>(part, Z, q_w, q_b, M, T);
  k4_out<<<dim3(N_ / 128, B_), 256, 0, stream>>>(M, T, q_feat, out);
}

// Round 2
// 187.346 us; speedup vs baseline: 1.6420x; 1.6420x over previous
//
#include <hip/hip_runtime.h>
#include <hip/hip_bf16.h>
#include <cstdint>

#define B_ 8
#define C_ 128
#define N_ 16384  // H*W

typedef __attribute__((ext_vector_type(8))) short short8;
typedef __attribute__((ext_vector_type(4))) float f32x4;
typedef __attribute__((ext_vector_type(4))) unsigned short us4;
typedef unsigned short u16;

__device__ __forceinline__ short f2bf(float f) {
  union { float f; unsigned u; } c; c.f = f;
  unsigned r = (c.u + 0x7FFFu + ((c.u >> 16) & 1u)) >> 16;
  return (short)r;
}

__device__ __forceinline__ unsigned cvtpk(float lo, float hi) {
  unsigned r;
  asm("v_cvt_pk_bf16_f32 %0, %1, %2" : "=v"(r) : "v"(lo), "v"(hi));
  return r;
}

union SB { short8 s8; unsigned u[4]; };

__device__ __forceinline__ void gl_lds16(const float* g, float* l) {
  __builtin_amdgcn_global_load_lds(
      (const __attribute__((address_space(1))) void*)g,
      (__attribute__((address_space(3))) void*)l, 16, 0, 0);
}

// ---------------------------------------------------------------------------
// K0: preconvert k_w, v_w (fp32) -> wbf (bf16 [2][128][128])
// ---------------------------------------------------------------------------
__global__ __launch_bounds__(256) void k0_wcvt(const float* __restrict__ kw,
                                               const float* __restrict__ vw,
                                               u16* __restrict__ wbf) {
  const int g = blockIdx.x * 256 + threadIdx.x;  // 0..8191 float4s
  const int mat = g >> 12, o4 = g & 4095;
  const float* src = mat ? vw : kw;
  float4 f = reinterpret_cast<const float4*>(src)[o4];
  us4 s;
  s[0] = (u16)f2bf(f.x); s[1] = (u16)f2bf(f.y);
  s[2] = (u16)f2bf(f.z); s[3] = (u16)f2bf(f.w);
  reinterpret_cast<us4*>(wbf + (size_t)mat * C_ * C_)[o4] = s;
}

// ---------------------------------------------------------------------------
// K1: EK = exp(k_w·x + k_b), V = v_w·x + v_b (bf16), Z[d] += sum_n EK
// grid (N/64, B), 256 thr = 4 waves; wave: (mat = w>>1, dhalf = w&1),
// covers 64 d x 64 n.  x-tile 128x64 fp32 staged via global_load_lds.
// ---------------------------------------------------------------------------
__global__ __launch_bounds__(256) void k1_proj(
    const float* __restrict__ kv, const u16* __restrict__ wbf,
    const float* __restrict__ kb, const float* __restrict__ vb,
    u16* __restrict__ EK, u16* __restrict__ V, float* __restrict__ Z) {
  __shared__ float xs[C_ * 64];  // [c][n] 32 KB
  const int b = blockIdx.y;
  const int n0 = blockIdx.x * 64;
  const int tid = threadIdx.x;
  const int wave = tid >> 6, lane = tid & 63;
  const int lg = lane >> 4, li = lane & 15;

  // stage 128x64 fp32 tile (each wave-instr: 4 rows x 256B)
  const float* xb = kv + (size_t)b * C_ * N_ + n0;
#pragma unroll
  for (int r = 0; r < 8; ++r) {
    const int row = r * 16 + wave * 4;
    const float* gp = xb + (size_t)(row + lg) * N_ + li * 4;
    float* lp = xs + row * 64;  // wave-uniform base; lane i -> +i*16B (linear)
    gl_lds16(gp, lp);
  }
  __syncthreads();

  const int mat = wave >> 1, dh = wave & 1;
  const int dbase = dh * 64;
  const u16* W = wbf + (size_t)mat * C_ * C_;

  f32x4 acc[4][4] = {};
#pragma unroll
  for (int ks = 0; ks < 4; ++ks) {
    const int c0 = ks * 32 + lg * 8;
    short8 a[4];
#pragma unroll
    for (int mt = 0; mt < 4; ++mt)
      a[mt] = *reinterpret_cast<const short8*>(W + (dbase + mt * 16 + li) * C_ + c0);
    float fb[4][8];
#pragma unroll
    for (int nt = 0; nt < 4; ++nt)
#pragma unroll
      for (int j = 0; j < 8; ++j)
        fb[nt][j] = xs[(c0 + j) * 64 + nt * 16 + li];
    short8 bf[4];
#pragma unroll
    for (int nt = 0; nt < 4; ++nt) {
      SB sb;
#pragma unroll
      for (int p = 0; p < 4; ++p) sb.u[p] = cvtpk(fb[nt][2 * p], fb[nt][2 * p + 1]);
      bf[nt] = sb.s8;
    }
#pragma unroll
    for (int mt = 0; mt < 4; ++mt)
#pragma unroll
      for (int nt = 0; nt < 4; ++nt)
        acc[mt][nt] = __builtin_amdgcn_mfma_f32_16x16x32_bf16(a[mt], bf[nt], acc[mt][nt], 0, 0, 0);
  }

  if (mat == 0) {
#pragma unroll
    for (int mt = 0; mt < 4; ++mt)
#pragma unroll
      for (int r = 0; r < 4; ++r) {
        const int d = dbase + mt * 16 + lg * 4 + r;
        const float kbias = kb[d];
        u16* ep = EK + ((size_t)b * C_ + d) * N_ + n0;
        float zp = 0.f;
#pragma unroll
        for (int nt = 0; nt < 4; ++nt) {
          const float ek = __expf(acc[mt][nt][r] + kbias);
          ep[nt * 16 + li] = (u16)f2bf(ek);
          zp += ek;
        }
#pragma unroll
        for (int off = 1; off < 16; off <<= 1) zp += __shfl_xor(zp, off);
        if (li == 0) atomicAdd(&Z[b * C_ + d], zp);
      }
  } else {
#pragma unroll
    for (int mt = 0; mt < 4; ++mt)
#pragma unroll
      for (int r = 0; r < 4; ++r) {
        const int d = dbase + mt * 16 + lg * 4 + r;
        const float vbias = vb[d];
        u16* vp = V + ((size_t)b * C_ + d) * N_ + n0;
#pragma unroll
        for (int nt = 0; nt < 4; ++nt)
          vp[nt * 16 + li] = (u16)f2bf(acc[mt][nt][r] + vbias);
      }
  }
}

// ---------------------------------------------------------------------------
// K2: context partials: part[kc][b][c][d] = sum_{n in chunk} V[c,n]*EK[d,n]
// (unchanged from round 1)
// ---------------------------------------------------------------------------
__global__ __launch_bounds__(512) void k2_ctx(const u16* __restrict__ EK,
                                              const u16* __restrict__ V,
                                              float* __restrict__ part) {
  const int b = blockIdx.y, kc = blockIdx.x;
  const int tid = threadIdx.x;
  const int wave = tid >> 6, lane = tid & 63;
  const int lg = lane >> 4, li = lane & 15;
  const u16* Vb = V + (size_t)b * C_ * N_;
  const u16* Eb = EK + (size_t)b * C_ * N_;
  f32x4 acc[8] = {};
#pragma unroll 4
  for (int s = 0; s < 16; ++s) {
    const int n0 = kc * 512 + s * 32 + lg * 8;
    short8 a = *reinterpret_cast<const short8*>(Vb + (size_t)(wave * 16 + li) * N_ + n0);
    short8 bf[8];
#pragma unroll
    for (int nt = 0; nt < 8; ++nt)
      bf[nt] = *reinterpret_cast<const short8*>(Eb + (size_t)(nt * 16 + li) * N_ + n0);
#pragma unroll
    for (int nt = 0; nt < 8; ++nt)
      acc[nt] = __builtin_amdgcn_mfma_f32_16x16x32_bf16(a, bf[nt], acc[nt], 0, 0, 0);
  }
  float* out = part + ((size_t)kc * B_ + b) * C_ * C_;
#pragma unroll
  for (int nt = 0; nt < 8; ++nt)
#pragma unroll
    for (int r = 0; r < 4; ++r) {
      const int c = wave * 16 + lg * 4 + r;
      const int d = nt * 16 + li;
      out[c * C_ + d] = acc[nt][r];
    }
}

// ---------------------------------------------------------------------------
// K3: cs = (sum_p part)/Z ; M = cs·q_w (bf16), T = cs·q_b  (unchanged)
// ---------------------------------------------------------------------------
__global__ __launch_bounds__(256) void k3_fin(const float* __restrict__ part,
                                              const float* __restrict__ Z,
                                              const float* __restrict__ qw,
                                              const float* __restrict__ qb,
                                              u16* __restrict__ M,
                                              float* __restrict__ T) {
  const int b = blockIdx.y;
  const int cs0 = blockIdx.x * 16;
  const int tid = threadIdx.x;
  __shared__ float cs[16][128];
#pragma unroll
  for (int i = 0; i < 8; ++i) {
    const int e = tid + i * 256;
    const int cl = e >> 7, d = e & 127;
    float s = 0.f;
    for (int p = 0; p < 32; ++p)
      s += part[(((size_t)p * B_ + b) * C_ + (cs0 + cl)) * C_ + d];
    cs[cl][d] = s / Z[b * C_ + d];
  }
  __syncthreads();
  const int cl = tid >> 4, e0 = (tid & 15) * 8;
  float m[8] = {};
  for (int d = 0; d < 128; ++d) {
    const float cv = cs[cl][d];
    const float* qr = qw + d * C_ + e0;
#pragma unroll
    for (int j = 0; j < 8; ++j) m[j] += cv * qr[j];
  }
  u16* mp = M + ((size_t)b * C_ + cs0 + cl) * C_ + e0;
#pragma unroll
  for (int j = 0; j < 8; ++j) mp[j] = (u16)f2bf(m[j]);
  if (tid < 16) {
    float tv = 0.f;
    for (int d = 0; d < 128; ++d) tv += cs[tid][d] * qb[d];
    T[b * C_ + cs0 + tid] = tv;
  }
}

// ---------------------------------------------------------------------------
// K4: out = M·q_feat + T (fp32). grid (N/64, B), 256 thr = 4 waves;
// wave covers 32 c x 64 n.  q-tile 128x64 fp32 staged via global_load_lds.
// ---------------------------------------------------------------------------
__global__ __launch_bounds__(256) void k4_out(const u16* __restrict__ M,
                                              const float* __restrict__ T,
                                              const float* __restrict__ q,
                                              float* __restrict__ out) {
  __shared__ float qs[C_ * 64];  // [d][n] 32 KB
  const int b = blockIdx.y;
  const int n0 = blockIdx.x * 64;
  const int tid = threadIdx.x;
  const int wave = tid >> 6, lane = tid & 63;
  const int lg = lane >> 4, li = lane & 15;

  const float* qbp = q + (size_t)b * C_ * N_ + n0;
#pragma unroll
  for (int r = 0; r < 8; ++r) {
    const int row = r * 16 + wave * 4;
    const float* gp = qbp + (size_t)(row + lg) * N_ + li * 4;
    float* lp = qs + row * 64;
    gl_lds16(gp, lp);
  }
  __syncthreads();

  const int cbase = wave * 32;
  const u16* Mb = M + (size_t)b * C_ * C_;
  f32x4 acc[2][4] = {};
#pragma unroll
  for (int ks = 0; ks < 4; ++ks) {
    const int d0 = ks * 32 + lg * 8;
    short8 a[2];
#pragma unroll
    for (int mt = 0; mt < 2; ++mt)
      a[mt] = *reinterpret_cast<const short8*>(Mb + (cbase + mt * 16 + li) * C_ + d0);
    float fb[4][8];
#pragma unroll
    for (int nt = 0; nt < 4; ++nt)
#pragma unroll
      for (int j = 0; j < 8; ++j)
        fb[nt][j] = qs[(d0 + j) * 64 + nt * 16 + li];
    short8 bf[4];
#pragma unroll
    for (int nt = 0; nt < 4; ++nt) {
      SB sb;
#pragma unroll
      for (int p = 0; p < 4; ++p) sb.u[p] = cvtpk(fb[nt][2 * p], fb[nt][2 * p + 1]);
      bf[nt] = sb.s8;
    }
#pragma unroll
    for (int mt = 0; mt < 2; ++mt)
#pragma unroll
      for (int nt = 0; nt < 4; ++nt)
        acc[mt][nt] = __builtin_amdgcn_mfma_f32_16x16x32_bf16(a[mt], bf[nt], acc[mt][nt], 0, 0, 0);
  }

#pragma unroll
  for (int mt = 0; mt < 2; ++mt)
#pragma unroll
    for (int r = 0; r < 4; ++r) {
      const int c = cbase + mt * 16 + lg * 4 + r;
      const float tc = T[b * C_ + c];
      float* op = out + ((size_t)b * C_ + c) * N_ + n0;
#pragma unroll
      for (int nt = 0; nt < 4; ++nt)
        op[nt * 16 + li] = acc[mt][nt][r] + tc;
    }
}

// ---------------------------------------------------------------------------
extern "C" void kernel_launch(void* const* d_in, const int* in_sizes, int n_in,
                              void* d_out, int out_size, void* d_ws, size_t ws_size,
                              hipStream_t stream) {
  const float* q_feat  = (const float*)d_in[0];
  const float* kv_feat = (const float*)d_in[1];
  const float* q_w = (const float*)d_in[2];
  const float* q_b = (const float*)d_in[3];
  const float* k_w = (const float*)d_in[4];
  const float* k_b = (const float*)d_in[5];
  const float* v_w = (const float*)d_in[6];
  const float* v_b = (const float*)d_in[7];
  float* out = (float*)d_out;

  char* ws = (char*)d_ws;
  const size_t szEV  = (size_t)B_ * C_ * N_ * sizeof(u16);        // 32 MB each
  const size_t szZ   = (size_t)B_ * C_ * sizeof(float);           // 4 KB
  const size_t szPar = (size_t)32 * B_ * C_ * C_ * sizeof(float); // 16 MB
  const size_t szM   = (size_t)B_ * C_ * C_ * sizeof(u16);        // 256 KB

  u16*   EK   = (u16*)ws;
  u16*   V    = (u16*)(ws + szEV);
  float* Z    = (float*)(ws + 2 * szEV);
  float* part = (float*)(ws + 2 * szEV + szZ);
  u16*   M    = (u16*)(ws + 2 * szEV + szZ + szPar);
  float* T    = (float*)(ws + 2 * szEV + szZ + szPar + szM);
  // wbf (bf16 weights, 64 KB) aliases the head of `part`: used only in K1,
  // which completes before K2 writes part (stream-ordered).
  u16*   wbf  = (u16*)part;

  hipMemsetAsync(Z, 0, szZ, stream);
  k0_wcvt<<<dim3(32), 256, 0, stream>>>(k_w, v_w, wbf);
  k1_proj<<<dim3(N_ / 64, B_), 256, 0, stream>>>(kv_feat, wbf, k_b, v_b, EK, V, Z);
  k2_ctx<<<dim3(32, B_), 512, 0, stream>>>(EK, V, part);
  k3_fin<<<dim3(8, B_), 256, 0, stream>>>(part, Z, q_w, q_b, M, T);
  k4_out<<<dim3(N_ / 64, B_), 256, 0, stream>>>(M, T, q_feat, out);
}

// Round 3
// 133.838 us; speedup vs baseline: 2.2985x; 1.3998x over previous
//
#include <hip/hip_runtime.h>
#include <hip/hip_bf16.h>
#include <cstdint>

#define B_ 8
#define C_ 128
#define N_ 16384  // H*W
#define CHN 256   // n per KA block
#define SN 128    // n per KA subtile
#define NC (N_ / CHN)  // 64 chunks

typedef __attribute__((ext_vector_type(8))) short short8;
typedef __attribute__((ext_vector_type(4))) float f32x4;
typedef __attribute__((ext_vector_type(4))) unsigned short us4;
typedef unsigned short u16;

__device__ __forceinline__ short f2bf(float f) {
  union { float f; unsigned u; } c; c.f = f;
  unsigned r = (c.u + 0x7FFFu + ((c.u >> 16) & 1u)) >> 16;
  return (short)r;
}

__device__ __forceinline__ unsigned cvtpk(float lo, float hi) {
  unsigned r;
  asm("v_cvt_pk_bf16_f32 %0, %1, %2" : "=v"(r) : "v"(lo), "v"(hi));
  return r;
}

union SB { short8 s8; unsigned u[4]; };

__device__ __forceinline__ void gl_lds16(const float* g, float* l) {
  __builtin_amdgcn_global_load_lds(
      (const __attribute__((address_space(1))) void*)g,
      (__attribute__((address_space(3))) void*)l, 16, 0, 0);
}

// ---------------------------------------------------------------------------
// K0: preconvert k_w, v_w (fp32) -> wbf (bf16 [2][128][128])
// ---------------------------------------------------------------------------
__global__ __launch_bounds__(256) void k0_wcvt(const float* __restrict__ kw,
                                               const float* __restrict__ vw,
                                               u16* __restrict__ wbf) {
  const int g = blockIdx.x * 256 + threadIdx.x;  // 0..8191 float4s
  const int mat = g >> 12, o4 = g & 4095;
  const float* src = mat ? vw : kw;
  float4 f = reinterpret_cast<const float4*>(src)[o4];
  us4 s;
  s[0] = (u16)f2bf(f.x); s[1] = (u16)f2bf(f.y);
  s[2] = (u16)f2bf(f.z); s[3] = (u16)f2bf(f.w);
  reinterpret_cast<us4*>(wbf + (size_t)mat * C_ * C_)[o4] = s;
}

// ---------------------------------------------------------------------------
// KA: fused projection + context partial.
// grid (NC, B), 512 thr = 8 waves.
// proj roles: mat = w>>2 (0:EK, 1:V), nsl = w&3 (32-n slice of subtile).
//   Swapped MFMA: A = x (rows n), B = W (cols d)  ->  D[n][d]:
//   lane holds 4 consecutive n at fixed d -> packed b64 stash writes.
// stash: [128 d][SN n] bf16 per matrix, byte ^= ((d&7)<<4) swizzle.
// ctx roles: cg = w>>1 (32-c), dh = w&1 (64-d): acc 32c x 64d.
// part[kc][b][c][d] fp32, zpart[kc][b][nsl][d] fp32 (no atomics).
// ---------------------------------------------------------------------------
__global__ __launch_bounds__(512) void ka_projctx(
    const float* __restrict__ kv, const u16* __restrict__ wbf,
    const float* __restrict__ kb, const float* __restrict__ vb,
    float* __restrict__ part, float* __restrict__ zpart) {
  __shared__ char lds[65536];
  float* xs  = (float*)lds;            // [128 c][SN n] fp32 (64 KB, phase 1)
  u16*  ek_s = (u16*)lds;              // [128 d][SN n] bf16 (32 KB, phase 2)
  u16*  v_s  = (u16*)(lds + 32768);    // [128 d][SN n] bf16 (32 KB, phase 2)

  const int b = blockIdx.y, kc = blockIdx.x;
  const int tid = threadIdx.x;
  const int w = tid >> 6, lane = tid & 63;
  const int lg = lane >> 4, li = lane & 15;
  const int mat = w >> 2, nsl = w & 3;
  const int cg = w >> 1, dh = w & 1;

  const float* xb = kv + (size_t)b * C_ * N_ + kc * CHN;
  const u16* W = wbf + (size_t)mat * C_ * C_;

  f32x4 ctx[2][4] = {};  // [am c-tile][bn d-tile]
  float z8[8] = {};      // EK waves: z per mt (d = mt*16+li)

  for (int st = 0; st < 2; ++st) {
    const int n0 = st * SN;
    // ---- phase 1: stage x tile 128c x 128n fp32 (64 KB) ----
#pragma unroll
    for (int i = 0; i < 8; ++i) {
      const int row = w * 16 + i * 2 + (lane >> 5);
      gl_lds16(xb + (size_t)row * N_ + n0 + (lane & 31) * 4,
               xs + (w * 16 + i * 2) * SN);
    }
    __syncthreads();

    // ---- phase 2: proj D[n][d] = x^T · W^T ----
    f32x4 pacc[2][8] = {};  // [nt][mt]
#pragma unroll
    for (int ks = 0; ks < 4; ++ks) {
      const int c0 = ks * 32 + lg * 8;
      short8 af[2];
#pragma unroll
      for (int nt = 0; nt < 2; ++nt) {
        const int n = nsl * 32 + nt * 16 + li;
        SB sb;
#pragma unroll
        for (int p = 0; p < 4; ++p)
          sb.u[p] = cvtpk(xs[(c0 + 2 * p) * SN + n], xs[(c0 + 2 * p + 1) * SN + n]);
        af[nt] = sb.s8;
      }
#pragma unroll
      for (int mt = 0; mt < 8; ++mt) {
        short8 bf = *reinterpret_cast<const short8*>(W + (mt * 16 + li) * C_ + c0);
#pragma unroll
        for (int nt = 0; nt < 2; ++nt)
          pacc[nt][mt] = __builtin_amdgcn_mfma_f32_16x16x32_bf16(af[nt], bf, pacc[nt][mt], 0, 0, 0);
      }
    }
    __syncthreads();  // all xs reads done before stash overwrites

    // ---- phase 3: bias (+exp for EK), pack, stash write ----
    {
      u16* S = mat ? v_s : ek_s;
      const float* bias_p = mat ? vb : kb;
#pragma unroll
      for (int mt = 0; mt < 8; ++mt) {
        const int d = mt * 16 + li;
        const float bias = bias_p[d];
#pragma unroll
        for (int nt = 0; nt < 2; ++nt) {
          float v0 = pacc[nt][mt][0] + bias;
          float v1 = pacc[nt][mt][1] + bias;
          float v2 = pacc[nt][mt][2] + bias;
          float v3 = pacc[nt][mt][3] + bias;
          if (mat == 0) {
            v0 = __expf(v0); v1 = __expf(v1); v2 = __expf(v2); v3 = __expf(v3);
            z8[mt] += v0 + v1 + v2 + v3;
          }
          const int nq = nsl * 32 + nt * 16 + lg * 4;  // n-quad base (in subtile)
          const unsigned byteoff = (unsigned)(d * (SN * 2) + ((nq * 2) ^ ((d & 7) << 4)));
          uint2 pk; pk.x = cvtpk(v0, v1); pk.y = cvtpk(v2, v3);
          *reinterpret_cast<uint2*>((char*)S + byteoff) = pk;
        }
      }
    }
    __syncthreads();

    // ---- phase 4: ctx += V · EK^T over this subtile's 128 n ----
#pragma unroll
    for (int kk = 0; kk < 4; ++kk) {
      const int nn = kk * 32 + lg * 8;  // K-octet
      short8 a[2], bb[4];
#pragma unroll
      for (int am = 0; am < 2; ++am) {
        const int c = cg * 32 + am * 16 + li;
        a[am] = *reinterpret_cast<const short8*>(
            (char*)v_s + c * (SN * 2) + ((nn * 2) ^ ((c & 7) << 4)));
      }
#pragma unroll
      for (int bn = 0; bn < 4; ++bn) {
        const int d = dh * 64 + bn * 16 + li;
        bb[bn] = *reinterpret_cast<const short8*>(
            (char*)ek_s + d * (SN * 2) + ((nn * 2) ^ ((d & 7) << 4)));
      }
#pragma unroll
      for (int am = 0; am < 2; ++am)
#pragma unroll
        for (int bn = 0; bn < 4; ++bn)
          ctx[am][bn] = __builtin_amdgcn_mfma_f32_16x16x32_bf16(a[am], bb[bn], ctx[am][bn], 0, 0, 0);
    }
    __syncthreads();  // stash consumed before next stage overwrite
  }

  // ---- epilogue: part + zpart (deterministic, no atomics) ----
  float* P = part + ((size_t)kc * B_ + b) * C_ * C_;
#pragma unroll
  for (int am = 0; am < 2; ++am)
#pragma unroll
    for (int bn = 0; bn < 4; ++bn)
#pragma unroll
      for (int r = 0; r < 4; ++r) {
        const int c = cg * 32 + am * 16 + lg * 4 + r;
        const int d = dh * 64 + bn * 16 + li;
        P[c * C_ + d] = ctx[am][bn][r];
      }
  if (mat == 0) {
#pragma unroll
    for (int mt = 0; mt < 8; ++mt) {
      float z = z8[mt];
      z += __shfl_xor(z, 16);
      z += __shfl_xor(z, 32);
      if (lg == 0)
        zpart[(((size_t)kc * B_ + b) * 4 + nsl) * C_ + mt * 16 + li] = z;
    }
  }
}

// ---------------------------------------------------------------------------
// KB: cs = (sum_kc part)/Z ; M = cs·q_w (bf16), T = cs·q_b
// grid (8, B), 256 thr; each block: 16 c-rows; Z = sum of zpart.
// ---------------------------------------------------------------------------
__global__ __launch_bounds__(256) void kb_fin(const float* __restrict__ part,
                                              const float* __restrict__ zpart,
                                              const float* __restrict__ qw,
                                              const float* __restrict__ qb,
                                              u16* __restrict__ M,
                                              float* __restrict__ T) {
  const int b = blockIdx.y;
  const int cs0 = blockIdx.x * 16;
  const int tid = threadIdx.x;
  __shared__ float cs[16][128];
  __shared__ float Zs[128];
  if (tid < 128) {
    float s = 0.f;
    for (int kc = 0; kc < NC; ++kc)
#pragma unroll
      for (int nsl = 0; nsl < 4; ++nsl)
        s += zpart[(((size_t)kc * B_ + b) * 4 + nsl) * C_ + tid];
    Zs[tid] = s;
  }
  __syncthreads();
#pragma unroll
  for (int i = 0; i < 8; ++i) {
    const int e = tid + i * 256;
    const int cl = e >> 7, d = e & 127;
    float s = 0.f;
    for (int p = 0; p < NC; ++p)
      s += part[(((size_t)p * B_ + b) * C_ + (cs0 + cl)) * C_ + d];
    cs[cl][d] = s / Zs[d];
  }
  __syncthreads();
  const int cl = tid >> 4, e0 = (tid & 15) * 8;
  float m[8] = {};
  for (int d = 0; d < 128; ++d) {
    const float cv = cs[cl][d];
    const float* qr = qw + d * C_ + e0;
#pragma unroll
    for (int j = 0; j < 8; ++j) m[j] += cv * qr[j];
  }
  u16* mp = M + ((size_t)b * C_ + cs0 + cl) * C_ + e0;
#pragma unroll
  for (int j = 0; j < 8; ++j) mp[j] = (u16)f2bf(m[j]);
  if (tid < 16) {
    float tv = 0.f;
    for (int d = 0; d < 128; ++d) tv += cs[tid][d] * qb[d];
    T[b * C_ + cs0 + tid] = tv;
  }
}

// ---------------------------------------------------------------------------
// K4: out = M·q_feat + T (fp32). grid (N/64, B), 256 thr = 4 waves
// (unchanged from round 2)
// ---------------------------------------------------------------------------
__global__ __launch_bounds__(256) void k4_out(const u16* __restrict__ M,
                                              const float* __restrict__ T,
                                              const float* __restrict__ q,
                                              float* __restrict__ out) {
  __shared__ float qs[C_ * 64];  // [d][n] 32 KB
  const int b = blockIdx.y;
  const int n0 = blockIdx.x * 64;
  const int tid = threadIdx.x;
  const int wave = tid >> 6, lane = tid & 63;
  const int lg = lane >> 4, li = lane & 15;

  const float* qbp = q + (size_t)b * C_ * N_ + n0;
#pragma unroll
  for (int r = 0; r < 8; ++r) {
    const int row = r * 16 + wave * 4;
    const float* gp = qbp + (size_t)(row + lg) * N_ + li * 4;
    float* lp = qs + row * 64;
    gl_lds16(gp, lp);
  }
  __syncthreads();

  const int cbase = wave * 32;
  const u16* Mb = M + (size_t)b * C_ * C_;
  f32x4 acc[2][4] = {};
#pragma unroll
  for (int ks = 0; ks < 4; ++ks) {
    const int d0 = ks * 32 + lg * 8;
    short8 a[2];
#pragma unroll
    for (int mt = 0; mt < 2; ++mt)
      a[mt] = *reinterpret_cast<const short8*>(Mb + (cbase + mt * 16 + li) * C_ + d0);
    float fb[4][8];
#pragma unroll
    for (int nt = 0; nt < 4; ++nt)
#pragma unroll
      for (int j = 0; j < 8; ++j)
        fb[nt][j] = qs[(d0 + j) * 64 + nt * 16 + li];
    short8 bf[4];
#pragma unroll
    for (int nt = 0; nt < 4; ++nt) {
      SB sb;
#pragma unroll
      for (int p = 0; p < 4; ++p) sb.u[p] = cvtpk(fb[nt][2 * p], fb[nt][2 * p + 1]);
      bf[nt] = sb.s8;
    }
#pragma unroll
    for (int mt = 0; mt < 2; ++mt)
#pragma unroll
      for (int nt = 0; nt < 4; ++nt)
        acc[mt][nt] = __builtin_amdgcn_mfma_f32_16x16x32_bf16(a[mt], bf[nt], acc[mt][nt], 0, 0, 0);
  }

#pragma unroll
  for (int mt = 0; mt < 2; ++mt)
#pragma unroll
    for (int r = 0; r < 4; ++r) {
      const int c = cbase + mt * 16 + lg * 4 + r;
      const float tc = T[b * C_ + c];
      float* op = out + ((size_t)b * C_ + c) * N_ + n0;
#pragma unroll
      for (int nt = 0; nt < 4; ++nt)
        op[nt * 16 + li] = acc[mt][nt][r] + tc;
    }
}

// ---------------------------------------------------------------------------
extern "C" void kernel_launch(void* const* d_in, const int* in_sizes, int n_in,
                              void* d_out, int out_size, void* d_ws, size_t ws_size,
                              hipStream_t stream) {
  const float* q_feat  = (const float*)d_in[0];
  const float* kv_feat = (const float*)d_in[1];
  const float* q_w = (const float*)d_in[2];
  const float* q_b = (const float*)d_in[3];
  const float* k_w = (const float*)d_in[4];
  const float* k_b = (const float*)d_in[5];
  const float* v_w = (const float*)d_in[6];
  const float* v_b = (const float*)d_in[7];
  float* out = (float*)d_out;

  char* ws = (char*)d_ws;
  const size_t szPart = (size_t)NC * B_ * C_ * C_ * sizeof(float);  // 32 MB
  const size_t szZp   = (size_t)NC * B_ * 4 * C_ * sizeof(float);   // 1 MB
  const size_t szWbf  = (size_t)2 * C_ * C_ * sizeof(u16);          // 64 KB
  const size_t szM    = (size_t)B_ * C_ * C_ * sizeof(u16);         // 256 KB

  float* part  = (float*)ws;
  float* zpart = (float*)(ws + szPart);
  u16*   wbf   = (u16*)(ws + szPart + szZp);
  u16*   M     = (u16*)(ws + szPart + szZp + szWbf);
  float* T     = (float*)(ws + szPart + szZp + szWbf + szM);

  k0_wcvt<<<dim3(32), 256, 0, stream>>>(k_w, v_w, wbf);
  ka_projctx<<<dim3(NC, B_), 512, 0, stream>>>(kv_feat, wbf, k_b, v_b, part, zpart);
  kb_fin<<<dim3(8, B_), 256, 0, stream>>>(part, zpart, q_w, q_b, M, T);
  k4_out<<<dim3(N_ / 64, B_), 256, 0, stream>>>(M, T, q_feat, out);
}